// Round 2
// baseline (535.179 us; speedup 1.0000x reference)
//
#include <hip/hip_runtime.h>
#include <hip/hip_bf16.h>
#include <math.h>

typedef __bf16 bf16x8 __attribute__((ext_vector_type(8)));
typedef float  f32x4  __attribute__((ext_vector_type(4)));
typedef __hip_bfloat16 bf16;

#define DIM  1024
#define MLPD 4096
#define NB   4
#define SEQ  2048
#define ROWS (NB * SEQ) /* 8192 */

__device__ __forceinline__ void gload_lds16(const void* g, void* l) {
  __builtin_amdgcn_global_load_lds(
      (__attribute__((address_space(1))) void*)(g),
      (__attribute__((address_space(3))) void*)(l), 16, 0, 0);
}

__device__ __forceinline__ void bar() {
  asm volatile("" ::: "memory");
  __builtin_amdgcn_s_barrier();
  asm volatile("" ::: "memory");
}

__device__ __forceinline__ bf16 to_bf16(float v) { return __float2bfloat16(v); }
__device__ __forceinline__ bf16 to_bf16(bf16 v)  { return v; }

// ---------------------------------------------------------------------------
// 256x256 8-phase GEMM: C[M][N] = A[M][K](bf16) @ Bt[N][K]^T(bf16)
// BK=64, 8 waves (2M x 4N), per-wave 128x64, st_16x32 LDS swizzle,
// counted vmcnt(4) once per K-tile, setprio around MFMA clusters.
// EPI: 0 = +bias -> bf16 | 1 = *scale -> fp32 | 2 = +resid -> fp32
//      3 = +bias,gelu -> bf16 | 4 = +bias+resid -> fp32
// Requires: M%256==0, N%256==0, K%64==0, K>=128; rows 16B-aligned.
// ---------------------------------------------------------------------------
template <int EPI>
__global__ __launch_bounds__(512) void gemm256(
    const bf16* __restrict__ A,  long aBatch, int lda,
    const bf16* __restrict__ Bt, long bBatch, int ldb,
    void* __restrict__ Cout,     long cBatch, int ldc,
    const float* __restrict__ bias,
    const float* __restrict__ resid, long rBatch, int ldr,
    int K, float scale)
{
  extern __shared__ char smem[];  // 128 KiB: [buf][A 32K | B 32K]
  const int  bz      = blockIdx.z;
  const long rowBase = (long)blockIdx.y * 256;
  const long colBase = (long)blockIdx.x * 256;
  const long ldaB = (long)lda * 2, ldbB = (long)ldb * 2;
  const char* Ag = (const char*)(A + bz * aBatch + rowBase * lda);
  const char* Bg = (const char*)(Bt + bz * bBatch + colBase * ldb);

  const int tid  = threadIdx.x;
  const int lane = tid & 63;
  const int wave = tid >> 6;
  const int wm = wave >> 2, wn = wave & 3;   // 2 x 4 wave grid
  const int fr = lane & 15, fq = lane >> 4;
  // swizzle: byte ^= ((byte>>9)&1)<<5 ; bit9 == (row>>2)&1 == (fr>>2)&1 here
  const int laneOff = (fr * 128 + fq * 16) ^ ((fr & 4) ? 32 : 0);
  // staging pre-swizzled source offsets (involution applied to source side)
  const int b0   = (tid * 16) ^ (((tid >> 5) & 1) << 5);
  const int srow = b0 >> 7;   // 0..63
  const int scb  = b0 & 127;
  const int NT = K >> 6;

  bf16x8 a[4][2], bv[2][2][2];
  f32x4 acc[8][4] = {};

#define STAGE(j, isB, half)                                                    \
  do {                                                                         \
    const char* _g  = (isB) ? Bg : Ag;                                         \
    const long  _ld = (isB) ? ldbB : ldaB;                                     \
    char* _l = smem + (((j) & 1) << 16) + ((isB) ? 32768 : 0) +                \
               ((half) << 14) + tid * 16;                                      \
    const char* _s = _g + (long)((half) * 128 + srow) * _ld + (j) * 128 + scb; \
    gload_lds16(_s, _l);                                                       \
    gload_lds16(_s + 64 * _ld, _l + 8192);                                     \
  } while (0)

#define LDA_H(mh)                                                              \
  do {                                                                         \
    const char* _b = smem + ((j & 1) << 16) + wm * 16384 + (mh) * 8192 + laneOff; \
    _Pragma("unroll") for (int m = 0; m < 4; ++m)                              \
      _Pragma("unroll") for (int kk = 0; kk < 2; ++kk)                         \
        a[m][kk] = *(const bf16x8*)(_b + m * 2048 + kk * 64);                  \
  } while (0)

#define LDB_H(nh)                                                              \
  do {                                                                         \
    const char* _b = smem + ((j & 1) << 16) + 32768 + wn * 8192 +              \
                     (nh) * 4096 + laneOff;                                    \
    _Pragma("unroll") for (int n = 0; n < 2; ++n)                              \
      _Pragma("unroll") for (int kk = 0; kk < 2; ++kk)                         \
        bv[nh][n][kk] = *(const bf16x8*)(_b + n * 2048 + kk * 64);             \
  } while (0)

#define MM(mh, nh)                                                             \
  do {                                                                         \
    __builtin_amdgcn_s_setprio(1);                                             \
    _Pragma("unroll") for (int m = 0; m < 4; ++m)                              \
      _Pragma("unroll") for (int n = 0; n < 2; ++n)                            \
        _Pragma("unroll") for (int kk = 0; kk < 2; ++kk)                       \
          acc[(mh) * 4 + m][(nh) * 2 + n] =                                    \
              __builtin_amdgcn_mfma_f32_16x16x32_bf16(                         \
                  a[m][kk], bv[nh][n][kk], acc[(mh) * 4 + m][(nh) * 2 + n],    \
                  0, 0, 0);                                                    \
    __builtin_amdgcn_s_setprio(0);                                             \
  } while (0)

#define LGKM0 asm volatile("s_waitcnt lgkmcnt(0)" ::: "memory")
#define VM4   asm volatile("s_waitcnt vmcnt(4)" ::: "memory")
#define VM0   asm volatile("s_waitcnt vmcnt(0)" ::: "memory")

  // Prologue: tile0 {A0,A1,B0,B1} + tile1 {B0,A0}; vmcnt(4) retires tile0.
  STAGE(0, 0, 0); STAGE(0, 0, 1); STAGE(0, 1, 0); STAGE(0, 1, 1);
  STAGE(1, 1, 0); STAGE(1, 0, 0);
  VM4; bar();

  for (int j = 0; j < NT; ++j) {
    // phase 1: quadrant (mh0,nh0); stage B1(j+1)
    LDA_H(0); LDB_H(0);
    if (j + 1 < NT) STAGE(j + 1, 1, 1);
    bar(); LGKM0; MM(0, 0); bar();
    // phase 2: (mh0,nh1); stage A1(j+1).  B-halves of cur dead after this.
    LDB_H(1);
    if (j + 1 < NT) STAGE(j + 1, 0, 1);
    bar(); LGKM0; MM(0, 1); bar();
    // phase 3: (mh1,nh1); stage B0(j+2) (overwrites cur B0: dead).
    LDA_H(1);
    if (j + 2 < NT) STAGE(j + 2, 1, 0);
    bar(); LGKM0; MM(1, 1); bar();
    // phase 4: (mh1,nh0); stage A0(j+2) (cur A0 dead after ph3).
    // vmcnt(4) leaves only ph3/ph4 stages in flight => tile j+1 resident.
    if (j + 2 < NT) { STAGE(j + 2, 0, 0); VM4; }
    else if (j + 1 < NT) { VM0; }
    bar(); MM(1, 0); bar();
  }

#undef STAGE
#undef LDA_H
#undef LDB_H
#undef MM

  // Epilogue (verified C/D mapping: col = ..+fr, row = ..+fq*4+e)
#pragma unroll
  for (int i = 0; i < 8; ++i) {
#pragma unroll
    for (int jn = 0; jn < 4; ++jn) {
      const long col = colBase + wn * 64 + jn * 16 + fr;
#pragma unroll
      for (int e = 0; e < 4; ++e) {
        const long r = rowBase + wm * 128 + i * 16 + fq * 4 + e;
        float v = acc[i][jn][e];
        if constexpr (EPI == 0) {
          v += bias[col];
          ((bf16*)Cout)[bz * cBatch + r * ldc + col] = __float2bfloat16(v);
        } else if constexpr (EPI == 1) {
          ((float*)Cout)[bz * cBatch + r * ldc + col] = v * scale;
        } else if constexpr (EPI == 2) {
          v += resid[bz * rBatch + r * ldr + col];
          ((float*)Cout)[bz * cBatch + r * ldc + col] = v;
        } else if constexpr (EPI == 3) {
          v += bias[col];
          const float gl = 0.5f * v * (1.0f + erff(v * 0.70710678118654752f));
          ((bf16*)Cout)[bz * cBatch + r * ldc + col] = __float2bfloat16(gl);
        } else {
          v += bias[col] + resid[r * (long)ldr + col];
          ((float*)Cout)[bz * cBatch + r * ldc + col] = v;
        }
      }
    }
  }
}

// ---------------------------------------------------------------------------
// LayerNorm over DIM=1024, one block per row, fp32 in -> bf16 out
// ---------------------------------------------------------------------------
__global__ __launch_bounds__(256) void ln_kernel(
    const float* __restrict__ x, const float* __restrict__ gamma,
    const float* __restrict__ beta, bf16* __restrict__ out)
{
  const long row = blockIdx.x;
  const float4 v = ((const float4*)(x + row * DIM))[threadIdx.x];
  float s  = v.x + v.y + v.z + v.w;
  float ss = v.x * v.x + v.y * v.y + v.z * v.z + v.w * v.w;
  const int lane = threadIdx.x & 63, wave = threadIdx.x >> 6;
#pragma unroll
  for (int o = 32; o; o >>= 1) { s += __shfl_xor(s, o); ss += __shfl_xor(ss, o); }
  __shared__ float rs[4], rss[4];
  if (lane == 0) { rs[wave] = s; rss[wave] = ss; }
  __syncthreads();
  s  = rs[0] + rs[1] + rs[2] + rs[3];
  ss = rss[0] + rss[1] + rss[2] + rss[3];
  const float mean = s * (1.0f / DIM);
  const float var  = ss * (1.0f / DIM) - mean * mean;
  const float rstd = rsqrtf(var + 1e-5f);
  const float4 g = ((const float4*)gamma)[threadIdx.x];
  const float4 b = ((const float4*)beta)[threadIdx.x];
  union { bf16 h[4]; uint2 u; } pk;
  pk.h[0] = __float2bfloat16(g.x * (v.x - mean) * rstd + b.x);
  pk.h[1] = __float2bfloat16(g.y * (v.y - mean) * rstd + b.y);
  pk.h[2] = __float2bfloat16(g.z * (v.z - mean) * rstd + b.z);
  pk.h[3] = __float2bfloat16(g.w * (v.w - mean) * rstd + b.w);
  ((uint2*)(out + row * DIM))[threadIdx.x] = pk.u;
}

// ---------------------------------------------------------------------------
// Row softmax over SEQ=2048 fp32 scores, write bf16 P in-place (row stride
// stays 8192 bytes => 4096 bf16 elements)
// ---------------------------------------------------------------------------
__global__ __launch_bounds__(256) void softmax_kernel(float* __restrict__ scores)
{
  const long row = blockIdx.x;
  float* rp = scores + row * (long)SEQ;
  const float4 v0 = ((const float4*)rp)[threadIdx.x * 2];
  const float4 v1 = ((const float4*)rp)[threadIdx.x * 2 + 1];
  float f[8] = {v0.x, v0.y, v0.z, v0.w, v1.x, v1.y, v1.z, v1.w};
  const int lane = threadIdx.x & 63, wave = threadIdx.x >> 6;
  float mx = f[0];
#pragma unroll
  for (int j = 1; j < 8; ++j) mx = fmaxf(mx, f[j]);
#pragma unroll
  for (int o = 32; o; o >>= 1) mx = fmaxf(mx, __shfl_xor(mx, o));
  __shared__ float rm[4], rsum[4];
  if (lane == 0) rm[wave] = mx;
  __syncthreads();
  mx = fmaxf(fmaxf(rm[0], rm[1]), fmaxf(rm[2], rm[3]));
  float sum = 0.0f;
#pragma unroll
  for (int j = 0; j < 8; ++j) { f[j] = expf(f[j] - mx); sum += f[j]; }
#pragma unroll
  for (int o = 32; o; o >>= 1) sum += __shfl_xor(sum, o);
  if (lane == 0) rsum[wave] = sum;
  __syncthreads();
  sum = rsum[0] + rsum[1] + rsum[2] + rsum[3];
  const float inv = 1.0f / sum;
  union { bf16 h[8]; uint4 u; } pk;
#pragma unroll
  for (int j = 0; j < 8; ++j) pk.h[j] = __float2bfloat16(f[j] * inv);
  bf16* prow = (bf16*)scores + row * (long)(2 * SEQ);
  ((uint4*)prow)[threadIdx.x] = pk.u;
}

// ---------------------------------------------------------------------------
// Tiled transpose + convert to bf16: out[c*ldOut + r] = in[r*ldIn + c]
// ---------------------------------------------------------------------------
template <typename TI>
__global__ __launch_bounds__(256) void transpose_bf16_kernel(
    const TI* __restrict__ in, bf16* __restrict__ out,
    int ldIn, int ldOut, long inBatch, long outBatch)
{
  __shared__ bf16 tile[32][33];
  const long zin  = (long)blockIdx.z * inBatch;
  const long zout = (long)blockIdx.z * outBatch;
  const int c0 = blockIdx.x * 32, r0 = blockIdx.y * 32;
  const int tx = threadIdx.x & 31, ty = threadIdx.x >> 5;  // 32 x 8
#pragma unroll
  for (int i = 0; i < 32; i += 8)
    tile[ty + i][tx] = to_bf16(in[zin + (long)(r0 + ty + i) * ldIn + c0 + tx]);
  __syncthreads();
#pragma unroll
  for (int i = 0; i < 32; i += 8)
    out[zout + (long)(c0 + ty + i) * ldOut + r0 + tx] = tile[tx][ty + i];
}

// concat bq|bk|bv -> bqkv[3072]
__global__ __launch_bounds__(256) void concat3_kernel(
    const float* __restrict__ a, const float* __restrict__ b,
    const float* __restrict__ c, float* __restrict__ o)
{
  const int i = blockIdx.x * 256 + threadIdx.x;
  if (i < DIM) { o[i] = a[i]; o[DIM + i] = b[i]; o[2 * DIM + i] = c[i]; }
}

// ---------------------------------------------------------------------------
extern "C" void kernel_launch(void* const* d_in, const int* in_sizes, int n_in,
                              void* d_out, int out_size, void* d_ws, size_t ws_size,
                              hipStream_t stream) {
  const float* x   = (const float*)d_in[0];
  const float* g1  = (const float*)d_in[1];
  const float* be1 = (const float*)d_in[2];
  const float* g2  = (const float*)d_in[3];
  const float* be2 = (const float*)d_in[4];
  const float* Wq  = (const float*)d_in[5];
  const float* bq  = (const float*)d_in[6];
  const float* Wk  = (const float*)d_in[7];
  const float* bk  = (const float*)d_in[8];
  const float* Wv  = (const float*)d_in[9];
  const float* bv  = (const float*)d_in[10];
  const float* W1  = (const float*)d_in[11];
  const float* b1  = (const float*)d_in[12];
  const float* W2  = (const float*)d_in[13];
  const float* b2  = (const float*)d_in[14];
  float* out = (float*)d_out;

  char* ws = (char*)d_ws;
  bf16* WqkvT = (bf16*)(ws + 0);            // 6 MiB  [3072][1024]
  bf16* W1T   = (bf16*)(ws + (6l << 20));   // 8 MiB  [4096][1024]
  bf16* W2T   = (bf16*)(ws + (14l << 20));  // 8 MiB  [1024][4096]
  float* bqkv = (float*)(ws + (22l << 20)); // 12 KiB
  bf16* h     = (bf16*)(ws + (23l << 20));  // 16 MiB [8192][1024]
  bf16* qkv   = (bf16*)(ws + (39l << 20));  // 48 MiB [8192][3072]
  bf16* vT    = (bf16*)(ws + (87l << 20));  // 16 MiB [4][1024][2048]
  float* sc   = (float*)(ws + (103l << 20)); // 64 MiB [4][2048][2048]
  bf16* P     = (bf16*)sc;                   // alias, row stride 4096
  bf16* g_act = (bf16*)sc;                   // alias, [8192][4096]

  const int SMEM = 131072;
  hipFuncSetAttribute(reinterpret_cast<const void*>(&gemm256<0>),
                      hipFuncAttributeMaxDynamicSharedMemorySize, SMEM);
  hipFuncSetAttribute(reinterpret_cast<const void*>(&gemm256<1>),
                      hipFuncAttributeMaxDynamicSharedMemorySize, SMEM);
  hipFuncSetAttribute(reinterpret_cast<const void*>(&gemm256<2>),
                      hipFuncAttributeMaxDynamicSharedMemorySize, SMEM);
  hipFuncSetAttribute(reinterpret_cast<const void*>(&gemm256<3>),
                      hipFuncAttributeMaxDynamicSharedMemorySize, SMEM);
  hipFuncSetAttribute(reinterpret_cast<const void*>(&gemm256<4>),
                      hipFuncAttributeMaxDynamicSharedMemorySize, SMEM);

  const dim3 blk(256), gblk(512);

  // weights -> bf16 transposed
  concat3_kernel<<<4, blk, 0, stream>>>(bq, bk, bv, bqkv);
  transpose_bf16_kernel<float><<<dim3(32, 32, 1), blk, 0, stream>>>(
      Wq, WqkvT, DIM, DIM, 0, 0);
  transpose_bf16_kernel<float><<<dim3(32, 32, 1), blk, 0, stream>>>(
      Wk, WqkvT + (long)DIM * DIM, DIM, DIM, 0, 0);
  transpose_bf16_kernel<float><<<dim3(32, 32, 1), blk, 0, stream>>>(
      Wv, WqkvT + 2l * DIM * DIM, DIM, DIM, 0, 0);
  transpose_bf16_kernel<float><<<dim3(128, 32, 1), blk, 0, stream>>>(
      W1, W1T, MLPD, DIM, 0, 0);
  transpose_bf16_kernel<float><<<dim3(32, 128, 1), blk, 0, stream>>>(
      W2, W2T, DIM, MLPD, 0, 0);

  // LN1
  ln_kernel<<<ROWS, blk, 0, stream>>>(x, g1, be1, h);

  // fused QKV: [8192][1024] @ [3072][1024]^T + bqkv -> qkv bf16
  gemm256<0><<<dim3(12, 32, 1), gblk, SMEM, stream>>>(
      h, 0, DIM, WqkvT, 0, DIM, qkv, 0, 3 * DIM,
      bqkv, nullptr, 0, 0, DIM, 1.0f);

  // v slice -> vT per batch
  transpose_bf16_kernel<bf16><<<dim3(32, 64, NB), blk, 0, stream>>>(
      qkv + 2 * DIM, vT, 3 * DIM, SEQ, (long)SEQ * 3 * DIM, (long)DIM * SEQ);

  // scores = q @ k^T * (1/32), fp32
  gemm256<1><<<dim3(8, 8, NB), gblk, SMEM, stream>>>(
      qkv, (long)SEQ * 3 * DIM, 3 * DIM, qkv + DIM, (long)SEQ * 3 * DIM, 3 * DIM,
      sc, (long)SEQ * SEQ, SEQ, nullptr, nullptr, 0, 0, DIM, 0.03125f);

  // softmax rows (bf16 out in-place, stride 4096)
  softmax_kernel<<<ROWS, blk, 0, stream>>>(sc);

  // x1 = P @ V + x -> d_out
  gemm256<2><<<dim3(4, 8, NB), gblk, SMEM, stream>>>(
      P, (long)SEQ * 2 * SEQ, 2 * SEQ, vT, (long)DIM * SEQ, SEQ,
      out, (long)SEQ * DIM, DIM, nullptr, x, (long)SEQ * DIM, DIM, SEQ, 1.0f);

  // LN2
  ln_kernel<<<ROWS, blk, 0, stream>>>(out, g2, be2, h);

  // MLP1: gelu(h @ W1 + b1) -> g_act bf16
  gemm256<3><<<dim3(16, 32, 1), gblk, SMEM, stream>>>(
      h, 0, DIM, W1T, 0, DIM, g_act, 0, MLPD, b1, nullptr, 0, 0, DIM, 1.0f);

  // MLP2: out = g_act @ W2 + b2 + x1
  gemm256<4><<<dim3(4, 32, 1), gblk, SMEM, stream>>>(
      g_act, 0, MLPD, W2T, 0, MLPD, out, 0, DIM, b2, out, 0, DIM, MLPD, 1.0f);
}

// Round 4
// 459.218 us; speedup vs baseline: 1.1654x; 1.1654x over previous
//
#include <hip/hip_runtime.h>
#include <hip/hip_bf16.h>
#include <math.h>

typedef __bf16 bf16x8 __attribute__((ext_vector_type(8)));
typedef float  f32x4  __attribute__((ext_vector_type(4)));
typedef __hip_bfloat16 bf16;

#define DIM  1024
#define MLPD 4096
#define NB   4
#define SEQ  2048
#define ROWS (NB * SEQ) /* 8192 */

__device__ __forceinline__ void gload_lds16(const void* g, void* l) {
  __builtin_amdgcn_global_load_lds(
      (__attribute__((address_space(1))) void*)(g),
      (__attribute__((address_space(3))) void*)(l), 16, 0, 0);
}

__device__ __forceinline__ void bar() {
  asm volatile("" ::: "memory");
  __builtin_amdgcn_s_barrier();
  asm volatile("" ::: "memory");
}

template <int N>
__device__ __forceinline__ void vmw() {
  asm volatile("s_waitcnt vmcnt(%0)" ::"n"(N) : "memory");
}

__device__ __forceinline__ bf16 to_bf16(float v) { return __float2bfloat16(v); }
__device__ __forceinline__ bf16 to_bf16(bf16 v)  { return v; }

// ---------------------------------------------------------------------------
// 256xBN 8-phase GEMM: C = A[M][K](bf16) @ Bt[N][K]^T(bf16).
// BK=64, 8 waves (2M x 4N), 3-bit XOR LDS swizzle (col ^= (row&7)<<4).
// Residency rule (round-3 post-mortem): waves touch BOTH A halves and BOTH B
// halves already at ph1 -> the ENTIRE tile j must be vmcnt-retired before
// ph1(j). A halves are read ph1..ph3, B halves ph1..ph2. Therefore:
//   - stage tile j+2's B halves at ph3(j), A halves at ph4(j) (regions dead,
//     ordered by LGKM0-before-barrier of the last reading phase)
//   - ONE vmcnt(L) at ph4(j) retires ALL of tile j+1 (issued 4-6 phases ago)
// EPI: 0=+bias->bf16 | 1=*scale->fp32 | 2=+resid->fp32 | 3=+bias,gelu->bf16
//      4=+bias+resid->fp32
// Requires: M%256==0, N%BN==0, K%64==0, NT=K/64>=4, rows 16B-aligned,
//           gridDim.x*y*z % 8 == 0 (XCD swizzle).
// ---------------------------------------------------------------------------
template <int EPI, int BN>
__global__ __launch_bounds__(512) void gemm256(
    const bf16* __restrict__ A,  long aBatch, int lda,
    const bf16* __restrict__ Bt, long bBatch, int ldb,
    void* __restrict__ Cout,     long cBatch, int ldc,
    const float* __restrict__ bias,
    const float* __restrict__ resid, long rBatch, int ldr,
    int K, float scale)
{
  extern __shared__ char smem[];  // 2 bufs x 64KiB stride: [A 32K | B <=32K]
  constexpr int NREP = BN / 128;            // B frags per half per wave
  constexpr int BLD = (BN == 256 ? 2 : 1);
  constexpr int L   = 4 + 2 * BLD;          // loads staged per tile per thread

  // bijective XCD-aware block swizzle (nwg % 8 == 0 guaranteed by launches)
  const int gx = gridDim.x, gy = gridDim.y;
  int flat = blockIdx.x + gx * (blockIdx.y + gy * blockIdx.z);
  const int nwg = gx * gy * gridDim.z;
  flat = (flat & 7) * (nwg >> 3) + (flat >> 3);
  const int bx = flat % gx;
  const int t2 = flat / gx;
  const int by = t2 % gy;
  const int bz = t2 / gy;

  const long rowBase = (long)by * 256;
  const long colBase = (long)bx * BN;
  const long ldaB = (long)lda * 2, ldbB = (long)ldb * 2;
  const char* Ag = (const char*)(A + bz * aBatch + rowBase * lda);
  const char* Bg = (const char*)(Bt + bz * bBatch + colBase * ldb);

  const int tid  = threadIdx.x;
  const int lane = tid & 63;
  const int wave = tid >> 6;
  const int wm = wave >> 2, wn = wave & 3;   // 2 x 4 wave grid
  const int fr = lane & 15, fq = lane >> 4;
  const int xr = (fr & 7) << 4;              // read-side swizzle
  const int srow = tid >> 3;                 // staging row 0..63
  const int scb  = (((tid & 7) ^ ((tid >> 3) & 7)) << 4);  // pre-swz src col
  const int NT = K >> 6;

  bf16x8 a[4][2], bv[2][NREP][2];
  f32x4 acc[8][2 * NREP] = {};

#define STAGE_A(J, half)                                                       \
  do {                                                                         \
    char* _l = smem + (((J) & 1) << 16) + (half) * 16384 + tid * 16;           \
    const char* _s = Ag + (long)((half) * 128 + srow) * ldaB + (J) * 128 + scb;\
    gload_lds16(_s, _l);                                                       \
    gload_lds16(_s + 64 * ldaB, _l + 8192);                                    \
  } while (0)

#define STAGE_B(J, half)                                                       \
  do {                                                                         \
    char* _l = smem + (((J) & 1) << 16) + 32768 + (half) * (BN << 6) + tid * 16;\
    const char* _s = Bg + (long)((half) * (BN >> 1) + srow) * ldbB +           \
                     (J) * 128 + scb;                                          \
    gload_lds16(_s, _l);                                                       \
    if constexpr (BN == 256) gload_lds16(_s + 64 * ldbB, _l + 8192);           \
  } while (0)

#define LDA_H(mh, J)                                                           \
  do {                                                                         \
    const char* _b = smem + (((J) & 1) << 16) + wm * 16384 + (mh) * 8192 +     \
                     fr * 128;                                                 \
    _Pragma("unroll") for (int m = 0; m < 4; ++m)                              \
      _Pragma("unroll") for (int kk = 0; kk < 2; ++kk)                         \
        a[m][kk] = *(const bf16x8*)(_b + m * 2048 +                            \
                                    (((fq << 4) | (kk << 6)) ^ xr));           \
  } while (0)

#define LDB_H(nh, J)                                                           \
  do {                                                                         \
    const char* _b = smem + (((J) & 1) << 16) + 32768 + wn * (BN << 5) +       \
                     (nh) * (BN << 4) + fr * 128;                              \
    _Pragma("unroll") for (int n = 0; n < NREP; ++n)                           \
      _Pragma("unroll") for (int kk = 0; kk < 2; ++kk)                         \
        bv[nh][n][kk] = *(const bf16x8*)(_b + n * 2048 +                       \
                                         (((fq << 4) | (kk << 6)) ^ xr));      \
  } while (0)

#define MM(mh, nh)                                                             \
  do {                                                                         \
    __builtin_amdgcn_s_setprio(1);                                             \
    _Pragma("unroll") for (int m = 0; m < 4; ++m)                              \
      _Pragma("unroll") for (int n = 0; n < NREP; ++n)                         \
        _Pragma("unroll") for (int kk = 0; kk < 2; ++kk)                       \
          acc[(mh) * 4 + m][(nh) * NREP + n] =                                 \
              __builtin_amdgcn_mfma_f32_16x16x32_bf16(                         \
                  a[m][kk], bv[nh][n][kk],                                     \
                  acc[(mh) * 4 + m][(nh) * NREP + n], 0, 0, 0);                \
    __builtin_amdgcn_s_setprio(0);                                             \
  } while (0)

#define LGKM0 asm volatile("s_waitcnt lgkmcnt(0)" ::: "memory")

  // Per tile J: whole tile resident at ph1 (retired by prior ph4's vmw).
  //  ph1: read A(mh0), B(nh0) | MFMA q(0,0)
  //  ph2: read B(nh1)         | MFMA q(0,1)   [B regions dead after]
  //  ph3: read A(mh1); stage B halves of J+2 | MFMA q(1,1) [A dead after]
  //  ph4: stage A halves of J+2; vmcnt(V4) -> tile J+1 fully retired | q(1,0)
#define TILE(J, STG, V4)                                                       \
  do {                                                                         \
    LDA_H(0, J); LDB_H(0, J);                                                  \
    bar(); LGKM0; MM(0, 0); bar();                                             \
    LDB_H(1, J);                                                               \
    bar(); LGKM0; MM(0, 1); bar();                                             \
    LDA_H(1, J);                                                               \
    if (STG) { STAGE_B((J) + 2, 0); STAGE_B((J) + 2, 1); }                     \
    bar(); LGKM0; MM(1, 1); bar();                                             \
    if (STG) { STAGE_A((J) + 2, 0); STAGE_A((J) + 2, 1); }                     \
    vmw<V4>(); bar(); MM(1, 0); bar();                                         \
  } while (0)

  // Prologue: tiles 0,1 in steady issue order [B0,B1,A0,A1] each;
  // vmw<L> retires all of tile 0.
  STAGE_B(0, 0); STAGE_B(0, 1); STAGE_A(0, 0); STAGE_A(0, 1);
  STAGE_B(1, 0); STAGE_B(1, 1); STAGE_A(1, 0); STAGE_A(1, 1);
  vmw<L>(); bar();

  for (int j = 0; j < NT - 2; ++j) TILE(j, true, L);
  TILE(NT - 2, false, 0);
  TILE(NT - 1, false, 63);

#undef STAGE_A
#undef STAGE_B
#undef LDA_H
#undef LDB_H
#undef MM
#undef TILE

  // Epilogue (C/D mapping: col = ..+fr, row = ..+fq*4+e)
#pragma unroll
  for (int i = 0; i < 8; ++i) {
#pragma unroll
    for (int nh = 0; nh < 2; ++nh) {
#pragma unroll
      for (int n = 0; n < NREP; ++n) {
        const long col = colBase + wn * (BN >> 2) + nh * (BN >> 3) + n * 16 + fr;
#pragma unroll
        for (int e = 0; e < 4; ++e) {
          const long r = rowBase + wm * 128 + i * 16 + fq * 4 + e;
          float v = acc[i][nh * NREP + n][e];
          if constexpr (EPI == 0) {
            v += bias[col];
            ((bf16*)Cout)[bz * cBatch + r * ldc + col] = __float2bfloat16(v);
          } else if constexpr (EPI == 1) {
            ((float*)Cout)[bz * cBatch + r * ldc + col] = v * scale;
          } else if constexpr (EPI == 2) {
            v += resid[bz * rBatch + r * ldr + col];
            ((float*)Cout)[bz * cBatch + r * ldc + col] = v;
          } else if constexpr (EPI == 3) {
            v += bias[col];
            const float gl = 0.5f * v * (1.0f + erff(v * 0.70710678118654752f));
            ((bf16*)Cout)[bz * cBatch + r * ldc + col] = __float2bfloat16(gl);
          } else {
            v += bias[col] + resid[r * (long)ldr + col];
            ((float*)Cout)[bz * cBatch + r * ldc + col] = v;
          }
        }
      }
    }
  }
}

// ---------------------------------------------------------------------------
// LayerNorm over DIM=1024, one block per row, fp32 in -> bf16 out
// ---------------------------------------------------------------------------
__global__ __launch_bounds__(256) void ln_kernel(
    const float* __restrict__ x, const float* __restrict__ gamma,
    const float* __restrict__ beta, bf16* __restrict__ out)
{
  const long row = blockIdx.x;
  const float4 v = ((const float4*)(x + row * DIM))[threadIdx.x];
  float s  = v.x + v.y + v.z + v.w;
  float ss = v.x * v.x + v.y * v.y + v.z * v.z + v.w * v.w;
  const int lane = threadIdx.x & 63, wave = threadIdx.x >> 6;
#pragma unroll
  for (int o = 32; o; o >>= 1) { s += __shfl_xor(s, o); ss += __shfl_xor(ss, o); }
  __shared__ float rs[4], rss[4];
  if (lane == 0) { rs[wave] = s; rss[wave] = ss; }
  __syncthreads();
  s  = rs[0] + rs[1] + rs[2] + rs[3];
  ss = rss[0] + rss[1] + rss[2] + rss[3];
  const float mean = s * (1.0f / DIM);
  const float var  = ss * (1.0f / DIM) - mean * mean;
  const float rstd = rsqrtf(var + 1e-5f);
  const float4 g = ((const float4*)gamma)[threadIdx.x];
  const float4 b = ((const float4*)beta)[threadIdx.x];
  union { bf16 h[4]; uint2 u; } pk;
  pk.h[0] = __float2bfloat16(g.x * (v.x - mean) * rstd + b.x);
  pk.h[1] = __float2bfloat16(g.y * (v.y - mean) * rstd + b.y);
  pk.h[2] = __float2bfloat16(g.z * (v.z - mean) * rstd + b.z);
  pk.h[3] = __float2bfloat16(g.w * (v.w - mean) * rstd + b.w);
  ((uint2*)(out + row * DIM))[threadIdx.x] = pk.u;
}

// ---------------------------------------------------------------------------
// Row softmax over SEQ=2048 fp32 scores, write bf16 P in-place (row stride
// stays 8192 bytes => 4096 bf16 elements)
// ---------------------------------------------------------------------------
__global__ __launch_bounds__(256) void softmax_kernel(float* __restrict__ scores)
{
  const long row = blockIdx.x;
  float* rp = scores + row * (long)SEQ;
  const float4 v0 = ((const float4*)rp)[threadIdx.x * 2];
  const float4 v1 = ((const float4*)rp)[threadIdx.x * 2 + 1];
  float f[8] = {v0.x, v0.y, v0.z, v0.w, v1.x, v1.y, v1.z, v1.w};
  const int lane = threadIdx.x & 63, wave = threadIdx.x >> 6;
  float mx = f[0];
#pragma unroll
  for (int j = 1; j < 8; ++j) mx = fmaxf(mx, f[j]);
#pragma unroll
  for (int o = 32; o; o >>= 1) mx = fmaxf(mx, __shfl_xor(mx, o));
  __shared__ float rm[4], rsum[4];
  if (lane == 0) rm[wave] = mx;
  __syncthreads();
  mx = fmaxf(fmaxf(rm[0], rm[1]), fmaxf(rm[2], rm[3]));
  float sum = 0.0f;
#pragma unroll
  for (int j = 0; j < 8; ++j) { f[j] = expf(f[j] - mx); sum += f[j]; }
#pragma unroll
  for (int o = 32; o; o >>= 1) sum += __shfl_xor(sum, o);
  if (lane == 0) rsum[wave] = sum;
  __syncthreads();
  sum = rsum[0] + rsum[1] + rsum[2] + rsum[3];
  const float inv = 1.0f / sum;
  union { bf16 h[8]; uint4 u; } pk;
#pragma unroll
  for (int j = 0; j < 8; ++j) pk.h[j] = __float2bfloat16(f[j] * inv);
  bf16* prow = (bf16*)scores + row * (long)(2 * SEQ);
  ((uint4*)prow)[threadIdx.x] = pk.u;
}

// ---------------------------------------------------------------------------
// Tiled transpose + convert to bf16: out[c*ldOut + r] = in[r*ldIn + c]
// ---------------------------------------------------------------------------
template <typename TI>
__global__ __launch_bounds__(256) void transpose_bf16_kernel(
    const TI* __restrict__ in, bf16* __restrict__ out,
    int ldIn, int ldOut, long inBatch, long outBatch)
{
  __shared__ bf16 tile[32][33];
  const long zin  = (long)blockIdx.z * inBatch;
  const long zout = (long)blockIdx.z * outBatch;
  const int c0 = blockIdx.x * 32, r0 = blockIdx.y * 32;
  const int tx = threadIdx.x & 31, ty = threadIdx.x >> 5;  // 32 x 8
#pragma unroll
  for (int i = 0; i < 32; i += 8)
    tile[ty + i][tx] = to_bf16(in[zin + (long)(r0 + ty + i) * ldIn + c0 + tx]);
  __syncthreads();
#pragma unroll
  for (int i = 0; i < 32; i += 8)
    out[zout + (long)(c0 + ty + i) * ldOut + r0 + tx] = tile[tx][ty + i];
}

// concat bq|bk|bv -> bqkv[3072]
__global__ __launch_bounds__(256) void concat3_kernel(
    const float* __restrict__ a, const float* __restrict__ b,
    const float* __restrict__ c, float* __restrict__ o)
{
  const int i = blockIdx.x * 256 + threadIdx.x;
  if (i < DIM) { o[i] = a[i]; o[DIM + i] = b[i]; o[2 * DIM + i] = c[i]; }
}

// ---------------------------------------------------------------------------
extern "C" void kernel_launch(void* const* d_in, const int* in_sizes, int n_in,
                              void* d_out, int out_size, void* d_ws, size_t ws_size,
                              hipStream_t stream) {
  const float* x   = (const float*)d_in[0];
  const float* g1  = (const float*)d_in[1];
  const float* be1 = (const float*)d_in[2];
  const float* g2  = (const float*)d_in[3];
  const float* be2 = (const float*)d_in[4];
  const float* Wq  = (const float*)d_in[5];
  const float* bq  = (const float*)d_in[6];
  const float* Wk  = (const float*)d_in[7];
  const float* bk  = (const float*)d_in[8];
  const float* Wv  = (const float*)d_in[9];
  const float* bv  = (const float*)d_in[10];
  const float* W1  = (const float*)d_in[11];
  const float* b1  = (const float*)d_in[12];
  const float* W2  = (const float*)d_in[13];
  const float* b2  = (const float*)d_in[14];
  float* out = (float*)d_out;

  char* ws = (char*)d_ws;
  bf16* WqkvT = (bf16*)(ws + 0);            // 6 MiB  [3072][1024]
  bf16* W1T   = (bf16*)(ws + (6l << 20));   // 8 MiB  [4096][1024]
  bf16* W2T   = (bf16*)(ws + (14l << 20));  // 8 MiB  [1024][4096]
  float* bqkv = (float*)(ws + (22l << 20)); // 12 KiB
  bf16* h     = (bf16*)(ws + (23l << 20));  // 16 MiB [8192][1024]
  bf16* qkv   = (bf16*)(ws + (39l << 20));  // 48 MiB [8192][3072]
  bf16* vT    = (bf16*)(ws + (87l << 20));  // 16 MiB [4][1024][2048]
  float* sc   = (float*)(ws + (103l << 20)); // 64 MiB [4][2048][2048]
  bf16* P     = (bf16*)sc;                   // alias, row stride 4096
  bf16* g_act = (bf16*)sc;                   // alias, [8192][4096]

  const int SMEM = 131072;
  hipFuncSetAttribute(reinterpret_cast<const void*>(&gemm256<0, 256>),
                      hipFuncAttributeMaxDynamicSharedMemorySize, SMEM);
  hipFuncSetAttribute(reinterpret_cast<const void*>(&gemm256<1, 256>),
                      hipFuncAttributeMaxDynamicSharedMemorySize, SMEM);
  hipFuncSetAttribute(reinterpret_cast<const void*>(&gemm256<2, 128>),
                      hipFuncAttributeMaxDynamicSharedMemorySize, SMEM);
  hipFuncSetAttribute(reinterpret_cast<const void*>(&gemm256<3, 256>),
                      hipFuncAttributeMaxDynamicSharedMemorySize, SMEM);
  hipFuncSetAttribute(reinterpret_cast<const void*>(&gemm256<4, 128>),
                      hipFuncAttributeMaxDynamicSharedMemorySize, SMEM);

  const dim3 blk(256), gblk(512);

  // weights -> bf16 transposed
  concat3_kernel<<<4, blk, 0, stream>>>(bq, bk, bv, bqkv);
  transpose_bf16_kernel<float><<<dim3(32, 32, 1), blk, 0, stream>>>(
      Wq, WqkvT, DIM, DIM, 0, 0);
  transpose_bf16_kernel<float><<<dim3(32, 32, 1), blk, 0, stream>>>(
      Wk, WqkvT + (long)DIM * DIM, DIM, DIM, 0, 0);
  transpose_bf16_kernel<float><<<dim3(32, 32, 1), blk, 0, stream>>>(
      Wv, WqkvT + 2l * DIM * DIM, DIM, DIM, 0, 0);
  transpose_bf16_kernel<float><<<dim3(128, 32, 1), blk, 0, stream>>>(
      W1, W1T, MLPD, DIM, 0, 0);
  transpose_bf16_kernel<float><<<dim3(32, 128, 1), blk, 0, stream>>>(
      W2, W2T, DIM, MLPD, 0, 0);

  // LN1
  ln_kernel<<<ROWS, blk, 0, stream>>>(x, g1, be1, h);

  // fused QKV: [8192][1024] @ [3072][1024]^T + bqkv -> qkv bf16 (384 wg)
  gemm256<0, 256><<<dim3(12, 32, 1), gblk, SMEM, stream>>>(
      h, 0, DIM, WqkvT, 0, DIM, qkv, 0, 3 * DIM,
      bqkv, nullptr, 0, 0, DIM, 1.0f);

  // v slice -> vT per batch
  transpose_bf16_kernel<bf16><<<dim3(32, 64, NB), blk, 0, stream>>>(
      qkv + 2 * DIM, vT, 3 * DIM, SEQ, (long)SEQ * 3 * DIM, (long)DIM * SEQ);

  // scores = q @ k^T * (1/32), fp32 (256 wg)
  gemm256<1, 256><<<dim3(8, 8, NB), gblk, SMEM, stream>>>(
      qkv, (long)SEQ * 3 * DIM, 3 * DIM, qkv + DIM, (long)SEQ * 3 * DIM, 3 * DIM,
      sc, (long)SEQ * SEQ, SEQ, nullptr, nullptr, 0, 0, DIM, 0.03125f);

  // softmax rows (bf16 out in-place, stride 4096)
  softmax_kernel<<<ROWS, blk, 0, stream>>>(sc);

  // x1 = P @ V + x -> d_out (BN=128 -> 256 wg)
  gemm256<2, 128><<<dim3(8, 8, NB), gblk, SMEM, stream>>>(
      P, (long)SEQ * 2 * SEQ, 2 * SEQ, vT, (long)DIM * SEQ, SEQ,
      out, (long)SEQ * DIM, DIM, nullptr, x, (long)SEQ * DIM, DIM, SEQ, 1.0f);

  // LN2
  ln_kernel<<<ROWS, blk, 0, stream>>>(out, g2, be2, h);

  // MLP1: gelu(h @ W1 + b1) -> g_act bf16 (512 wg)
  gemm256<3, 256><<<dim3(16, 32, 1), gblk, SMEM, stream>>>(
      h, 0, DIM, W1T, 0, DIM, g_act, 0, MLPD, b1, nullptr, 0, 0, DIM, 1.0f);

  // MLP2: out = g_act @ W2 + b2 + x1 (BN=128 -> 256 wg)
  gemm256<4, 128><<<dim3(8, 32, 1), gblk, SMEM, stream>>>(
      g_act, 0, MLPD, W2T, 0, MLPD, out, 0, DIM, b2, out, 0, DIM, MLPD, 1.0f);
}

// Round 6
// 387.661 us; speedup vs baseline: 1.3805x; 1.1846x over previous
//
#include <hip/hip_runtime.h>
#include <hip/hip_bf16.h>
#include <math.h>

typedef __bf16 bf16x8 __attribute__((ext_vector_type(8)));
typedef float  f32x4  __attribute__((ext_vector_type(4)));
typedef __hip_bfloat16 bf16;

#define DIM  1024
#define MLPD 4096
#define NB   4
#define SEQ  2048
#define ROWS (NB * SEQ) /* 8192 */

__device__ __forceinline__ void gload_lds16(const void* g, void* l) {
  __builtin_amdgcn_global_load_lds(
      (__attribute__((address_space(1))) void*)(g),
      (__attribute__((address_space(3))) void*)(l), 16, 0, 0);
}

__device__ __forceinline__ void bar() {
  asm volatile("" ::: "memory");
  __builtin_amdgcn_s_barrier();
  asm volatile("" ::: "memory");
}

__device__ __forceinline__ void vm0() {
  asm volatile("s_waitcnt vmcnt(0)" ::: "memory");
}

__device__ __forceinline__ bf16 to_bf16(float v) { return __float2bfloat16(v); }
__device__ __forceinline__ bf16 to_bf16(bf16 v)  { return v; }

// ---------------------------------------------------------------------------
// 128x128 GEMM, BK=32, 4 waves (2x2), 32 KiB LDS double-buffer -> 4 blocks/CU.
// 2-phase loop: per K-tile {stage next -> other buf; 8 ds_read (base+imm,
// slot-XOR swizzle); 16 MFMA; vmcnt(0); s_barrier}. TLP across 4 blocks/CU.
// LDS per buf: A[128r][64B] @0, B @8192; LDS[r][s] = global k-chunk s^(r&3).
// Staging chunks: 16 rows x 64B = 1024B; thread stages chunks c0=wave*2 and
// c0+1 at doff and doff+1024 (round-5 bug: was +2048 -> uninit/overlap LDS).
// EPI: 0=+bias->bf16 | 1=*scale->fp32 | 2=+resid->fp32 | 3=+bias,gelu->bf16
//      4=+bias+resid->fp32
// Requires: M%128==0, N%128==0, K%64==0, gx%8==0, gy%8==0.
// ---------------------------------------------------------------------------
template <int EPI>
__global__ __launch_bounds__(256, 4) void gemm128(
    const bf16* __restrict__ A,  long aBatch, int lda,
    const bf16* __restrict__ Bt, long bBatch, int ldb,
    void* __restrict__ Cout,     long cBatch, int ldc,
    const float* __restrict__ bias,
    const float* __restrict__ resid, long rBatch, int ldr,
    int K, float scale)
{
  __shared__ char smem[2][16384];

  // ---- block swizzle: XCD chunking over 8x8 super-tile order
  const int gx = gridDim.x, gy = gridDim.y;
  const int n = gx * gy * gridDim.z;
  const int f = blockIdx.x + gx * (blockIdx.y + gy * blockIdx.z);
  const int o = (f & 7) * (n >> 3) + (f >> 3);   // bijective, n%8==0
  const int sx = gx >> 3;
  int st = o >> 6;
  const int w = o & 63;
  const int spz = sx * (gy >> 3);
  const int bz = st / spz; st -= bz * spz;
  const int sty = st / sx, stx = st - sty * sx;
  const int by = sty * 8 + (w >> 3), bx = stx * 8 + (w & 7);

  const long rowBase = (long)by * 128;
  const long colBase = (long)bx * 128;
  const long ldaB = (long)lda * 2, ldbB = (long)ldb * 2;
  const char* Ag = (const char*)(A + bz * aBatch + rowBase * lda);
  const char* Bg = (const char*)(Bt + bz * bBatch + colBase * ldb);

  const int tid  = threadIdx.x;
  const int lane = tid & 63;
  const int wave = tid >> 6;
  const int wm = wave >> 1, wn = wave & 1;   // 2x2 wave grid, 64x64 each
  const int fr = lane & 15, fq = lane >> 4;

  // fragment read bases (one VALU base; all reads base + imm)
  const int sslot = (fq ^ (fr & 3)) << 4;
  const int abase = ((wm * 64 + fr) << 6) + sslot;
  const int bbase = ((wn * 64 + fr) << 6) + sslot + 8192;

  // staging: 2 chunks/thread/operand; chunk = 16 rows x 64B = 1024B
  const int c0   = wave * 2;
  const int swz  = ((lane & 3) ^ ((lane >> 2) & 3)) << 4;  // pre-swz src slot
  const int srow = lane >> 2;
  const char* aSrc0 = Ag + (long)(c0 * 16 + srow) * ldaB + swz;
  const char* aSrc1 = aSrc0 + 16 * ldaB;
  const char* bSrc0 = Bg + (long)(c0 * 16 + srow) * ldbB + swz;
  const char* bSrc1 = bSrc0 + 16 * ldbB;
  const int doff = c0 * 1024 + lane * 16;

  const int NT = K >> 5;
  f32x4 acc[4][4] = {};

#define STAGE(WB)                                                              \
  do {                                                                         \
    gload_lds16(aSrc0, &smem[WB][doff]);                                       \
    gload_lds16(aSrc1, &smem[WB][doff + 1024]);                                \
    gload_lds16(bSrc0, &smem[WB][8192 + doff]);                                \
    gload_lds16(bSrc1, &smem[WB][8192 + doff + 1024]);                         \
    aSrc0 += 64; aSrc1 += 64; bSrc0 += 64; bSrc1 += 64;                        \
  } while (0)

#define TILE(T, RB, WB)                                                        \
  do {                                                                         \
    if ((T) + 1 < NT) STAGE(WB);                                               \
    bf16x8 av[4], bv[4];                                                       \
    _Pragma("unroll") for (int m = 0; m < 4; ++m)                              \
      av[m] = *(const bf16x8*)(&smem[RB][0] + abase + m * 1024);               \
    _Pragma("unroll") for (int nn = 0; nn < 4; ++nn)                           \
      bv[nn] = *(const bf16x8*)(&smem[RB][0] + bbase + nn * 1024);             \
    __builtin_amdgcn_s_setprio(1);                                             \
    _Pragma("unroll") for (int m = 0; m < 4; ++m)                              \
      _Pragma("unroll") for (int nn = 0; nn < 4; ++nn)                         \
        acc[m][nn] = __builtin_amdgcn_mfma_f32_16x16x32_bf16(                  \
            av[m], bv[nn], acc[m][nn], 0, 0, 0);                               \
    __builtin_amdgcn_s_setprio(0);                                             \
    vm0(); bar();                                                              \
  } while (0)

  // prologue: tile 0 -> buf0
  STAGE(0);
  vm0(); bar();

  for (int t = 0; t < NT; t += 2) {
    TILE(t, 0, 1);
    TILE(t + 1, 1, 0);
  }

#undef STAGE
#undef TILE

  // Epilogue (C/D mapping: col = ..+fr, row = ..+fq*4+e) — r1-verified
#pragma unroll
  for (int m = 0; m < 4; ++m) {
#pragma unroll
    for (int nn = 0; nn < 4; ++nn) {
      const long col = colBase + wn * 64 + nn * 16 + fr;
#pragma unroll
      for (int e = 0; e < 4; ++e) {
        const long r = rowBase + wm * 64 + m * 16 + fq * 4 + e;
        float v = acc[m][nn][e];
        if constexpr (EPI == 0) {
          v += bias[col];
          ((bf16*)Cout)[bz * cBatch + r * ldc + col] = __float2bfloat16(v);
        } else if constexpr (EPI == 1) {
          ((float*)Cout)[bz * cBatch + r * ldc + col] = v * scale;
        } else if constexpr (EPI == 2) {
          v += resid[bz * rBatch + r * ldr + col];
          ((float*)Cout)[bz * cBatch + r * ldc + col] = v;
        } else if constexpr (EPI == 3) {
          v += bias[col];
          const float gl = 0.5f * v * (1.0f + erff(v * 0.70710678118654752f));
          ((bf16*)Cout)[bz * cBatch + r * ldc + col] = __float2bfloat16(gl);
        } else {
          v += bias[col] + resid[r * (long)ldr + col];
          ((float*)Cout)[bz * cBatch + r * ldc + col] = v;
        }
      }
    }
  }
}

// ---------------------------------------------------------------------------
// LayerNorm over DIM=1024, one block per row, fp32 in -> bf16 out
// ---------------------------------------------------------------------------
__global__ __launch_bounds__(256) void ln_kernel(
    const float* __restrict__ x, const float* __restrict__ gamma,
    const float* __restrict__ beta, bf16* __restrict__ out)
{
  const long row = blockIdx.x;
  const float4 v = ((const float4*)(x + row * DIM))[threadIdx.x];
  float s  = v.x + v.y + v.z + v.w;
  float ss = v.x * v.x + v.y * v.y + v.z * v.z + v.w * v.w;
  const int lane = threadIdx.x & 63, wave = threadIdx.x >> 6;
#pragma unroll
  for (int o = 32; o; o >>= 1) { s += __shfl_xor(s, o); ss += __shfl_xor(ss, o); }
  __shared__ float rs[4], rss[4];
  if (lane == 0) { rs[wave] = s; rss[wave] = ss; }
  __syncthreads();
  s  = rs[0] + rs[1] + rs[2] + rs[3];
  ss = rss[0] + rss[1] + rss[2] + rss[3];
  const float mean = s * (1.0f / DIM);
  const float var  = ss * (1.0f / DIM) - mean * mean;
  const float rstd = rsqrtf(var + 1e-5f);
  const float4 g = ((const float4*)gamma)[threadIdx.x];
  const float4 b = ((const float4*)beta)[threadIdx.x];
  union { bf16 h[4]; uint2 u; } pk;
  pk.h[0] = __float2bfloat16(g.x * (v.x - mean) * rstd + b.x);
  pk.h[1] = __float2bfloat16(g.y * (v.y - mean) * rstd + b.y);
  pk.h[2] = __float2bfloat16(g.z * (v.z - mean) * rstd + b.z);
  pk.h[3] = __float2bfloat16(g.w * (v.w - mean) * rstd + b.w);
  ((uint2*)(out + row * DIM))[threadIdx.x] = pk.u;
}

// ---------------------------------------------------------------------------
// Row softmax over SEQ=2048 fp32 scores, write bf16 P in-place (row stride
// stays 8192 bytes => 4096 bf16 elements)
// ---------------------------------------------------------------------------
__global__ __launch_bounds__(256) void softmax_kernel(float* __restrict__ scores)
{
  const long row = blockIdx.x;
  float* rp = scores + row * (long)SEQ;
  const float4 v0 = ((const float4*)rp)[threadIdx.x * 2];
  const float4 v1 = ((const float4*)rp)[threadIdx.x * 2 + 1];
  float f[8] = {v0.x, v0.y, v0.z, v0.w, v1.x, v1.y, v1.z, v1.w};
  const int lane = threadIdx.x & 63, wave = threadIdx.x >> 6;
  float mx = f[0];
#pragma unroll
  for (int j = 1; j < 8; ++j) mx = fmaxf(mx, f[j]);
#pragma unroll
  for (int o = 32; o; o >>= 1) mx = fmaxf(mx, __shfl_xor(mx, o));
  __shared__ float rm[4], rsum[4];
  if (lane == 0) rm[wave] = mx;
  __syncthreads();
  mx = fmaxf(fmaxf(rm[0], rm[1]), fmaxf(rm[2], rm[3]));
  float sum = 0.0f;
#pragma unroll
  for (int j = 0; j < 8; ++j) { f[j] = expf(f[j] - mx); sum += f[j]; }
#pragma unroll
  for (int o = 32; o; o >>= 1) sum += __shfl_xor(sum, o);
  if (lane == 0) rsum[wave] = sum;
  __syncthreads();
  sum = rsum[0] + rsum[1] + rsum[2] + rsum[3];
  const float inv = 1.0f / sum;
  union { bf16 h[8]; uint4 u; } pk;
#pragma unroll
  for (int j = 0; j < 8; ++j) pk.h[j] = __float2bfloat16(f[j] * inv);
  bf16* prow = (bf16*)scores + row * (long)(2 * SEQ);
  ((uint4*)prow)[threadIdx.x] = pk.u;
}

// ---------------------------------------------------------------------------
// Tiled transpose + convert to bf16: out[c*ldOut + r] = in[r*ldIn + c]
// ---------------------------------------------------------------------------
template <typename TI>
__global__ __launch_bounds__(256) void transpose_bf16_kernel(
    const TI* __restrict__ in, bf16* __restrict__ out,
    int ldIn, int ldOut, long inBatch, long outBatch)
{
  __shared__ bf16 tile[32][33];
  const long zin  = (long)blockIdx.z * inBatch;
  const long zout = (long)blockIdx.z * outBatch;
  const int c0 = blockIdx.x * 32, r0 = blockIdx.y * 32;
  const int tx = threadIdx.x & 31, ty = threadIdx.x >> 5;  // 32 x 8
#pragma unroll
  for (int i = 0; i < 32; i += 8)
    tile[ty + i][tx] = to_bf16(in[zin + (long)(r0 + ty + i) * ldIn + c0 + tx]);
  __syncthreads();
#pragma unroll
  for (int i = 0; i < 32; i += 8)
    out[zout + (long)(c0 + ty + i) * ldOut + r0 + tx] = tile[tx][ty + i];
}

// concat bq|bk|bv -> bqkv[3072]
__global__ __launch_bounds__(256) void concat3_kernel(
    const float* __restrict__ a, const float* __restrict__ b,
    const float* __restrict__ c, float* __restrict__ o)
{
  const int i = blockIdx.x * 256 + threadIdx.x;
  if (i < DIM) { o[i] = a[i]; o[DIM + i] = b[i]; o[2 * DIM + i] = c[i]; }
}

// ---------------------------------------------------------------------------
extern "C" void kernel_launch(void* const* d_in, const int* in_sizes, int n_in,
                              void* d_out, int out_size, void* d_ws, size_t ws_size,
                              hipStream_t stream) {
  const float* x   = (const float*)d_in[0];
  const float* g1  = (const float*)d_in[1];
  const float* be1 = (const float*)d_in[2];
  const float* g2  = (const float*)d_in[3];
  const float* be2 = (const float*)d_in[4];
  const float* Wq  = (const float*)d_in[5];
  const float* bq  = (const float*)d_in[6];
  const float* Wk  = (const float*)d_in[7];
  const float* bk  = (const float*)d_in[8];
  const float* Wv  = (const float*)d_in[9];
  const float* bv  = (const float*)d_in[10];
  const float* W1  = (const float*)d_in[11];
  const float* b1  = (const float*)d_in[12];
  const float* W2  = (const float*)d_in[13];
  const float* b2  = (const float*)d_in[14];
  float* out = (float*)d_out;

  char* ws = (char*)d_ws;
  bf16* WqkvT = (bf16*)(ws + 0);            // 6 MiB  [3072][1024]
  bf16* W1T   = (bf16*)(ws + (6l << 20));   // 8 MiB  [4096][1024]
  bf16* W2T   = (bf16*)(ws + (14l << 20));  // 8 MiB  [1024][4096]
  float* bqkv = (float*)(ws + (22l << 20)); // 12 KiB
  bf16* h     = (bf16*)(ws + (23l << 20));  // 16 MiB [8192][1024]
  bf16* qkv   = (bf16*)(ws + (39l << 20));  // 48 MiB [8192][3072]
  bf16* vT    = (bf16*)(ws + (87l << 20));  // 16 MiB [4][1024][2048]
  float* sc   = (float*)(ws + (103l << 20)); // 64 MiB [4][2048][2048]
  bf16* P     = (bf16*)sc;                   // alias, row stride 4096
  bf16* g_act = (bf16*)sc;                   // alias, [8192][4096]

  const dim3 blk(256);

  // weights -> bf16 transposed
  concat3_kernel<<<4, blk, 0, stream>>>(bq, bk, bv, bqkv);
  transpose_bf16_kernel<float><<<dim3(32, 32, 1), blk, 0, stream>>>(
      Wq, WqkvT, DIM, DIM, 0, 0);
  transpose_bf16_kernel<float><<<dim3(32, 32, 1), blk, 0, stream>>>(
      Wk, WqkvT + (long)DIM * DIM, DIM, DIM, 0, 0);
  transpose_bf16_kernel<float><<<dim3(32, 32, 1), blk, 0, stream>>>(
      Wv, WqkvT + 2l * DIM * DIM, DIM, DIM, 0, 0);
  transpose_bf16_kernel<float><<<dim3(128, 32, 1), blk, 0, stream>>>(
      W1, W1T, MLPD, DIM, 0, 0);
  transpose_bf16_kernel<float><<<dim3(32, 128, 1), blk, 0, stream>>>(
      W2, W2T, DIM, MLPD, 0, 0);

  // LN1
  ln_kernel<<<ROWS, blk, 0, stream>>>(x, g1, be1, h);

  // fused QKV: [8192][1024] @ [3072][1024]^T + bqkv -> qkv bf16
  gemm128<0><<<dim3(24, 64, 1), blk, 0, stream>>>(
      h, 0, DIM, WqkvT, 0, DIM, qkv, 0, 3 * DIM,
      bqkv, nullptr, 0, 0, DIM, 1.0f);

  // v slice -> vT per batch
  transpose_bf16_kernel<bf16><<<dim3(32, 64, NB), blk, 0, stream>>>(
      qkv + 2 * DIM, vT, 3 * DIM, SEQ, (long)SEQ * 3 * DIM, (long)DIM * SEQ);

  // scores = q @ k^T * (1/32), fp32
  gemm128<1><<<dim3(16, 16, NB), blk, 0, stream>>>(
      qkv, (long)SEQ * 3 * DIM, 3 * DIM, qkv + DIM, (long)SEQ * 3 * DIM, 3 * DIM,
      sc, (long)SEQ * SEQ, SEQ, nullptr, nullptr, 0, 0, DIM, 0.03125f);

  // softmax rows (bf16 out in-place, stride 4096)
  softmax_kernel<<<ROWS, blk, 0, stream>>>(sc);

  // x1 = P @ V + x -> d_out
  gemm128<2><<<dim3(8, 16, NB), blk, 0, stream>>>(
      P, (long)SEQ * 2 * SEQ, 2 * SEQ, vT, (long)DIM * SEQ, SEQ,
      out, (long)SEQ * DIM, DIM, nullptr, x, (long)SEQ * DIM, DIM, SEQ, 1.0f);

  // LN2
  ln_kernel<<<ROWS, blk, 0, stream>>>(out, g2, be2, h);

  // MLP1: gelu(h @ W1 + b1) -> g_act bf16
  gemm128<3><<<dim3(32, 64, 1), blk, 0, stream>>>(
      h, 0, DIM, W1T, 0, DIM, g_act, 0, MLPD, b1, nullptr, 0, 0, DIM, 1.0f);

  // MLP2: out = g_act @ W2 + b2 + x1
  gemm128<4><<<dim3(8, 64, 1), blk, 0, stream>>>(
      g_act, 0, MLPD, W2T, 0, MLPD, out, 0, DIM, b2, out, 0, DIM, MLPD, 1.0f);
}